// Round 3
// baseline (71.126 us; speedup 1.0000x reference)
//
#include <hip/hip_runtime.h>

#define NSAMP 65536
#define DTF 1e-5f

// ---------- complex helpers (float2 = complex64) ----------
__device__ __forceinline__ float2 cmul(float2 a, float2 b) {
    return make_float2(a.x * b.x - a.y * b.y, a.x * b.y + a.y * b.x);
}
__device__ __forceinline__ float2 cmac(float2 c, float2 a, float2 b) {
    c.x += a.x * b.x - a.y * b.y;
    c.y += a.x * b.y + a.y * b.x;
    return c;
}
__device__ __forceinline__ float2 cmulc(float2 a, float2 b) { // a * conj(b)
    return make_float2(a.x * b.x + a.y * b.y, a.y * b.x - a.x * b.y);
}

// ---------- 4x4 complex matmul C = A*B (row-major, 16 float2) ----------
__device__ __forceinline__ void mm4(const float2* A, const float2* B, float2* C) {
#pragma unroll
    for (int a = 0; a < 4; ++a) {
#pragma unroll
        for (int b = 0; b < 4; ++b) {
            float2 acc = cmul(A[a * 4 + 0], B[0 * 4 + b]);
            acc = cmac(acc, A[a * 4 + 1], B[1 * 4 + b]);
            acc = cmac(acc, A[a * 4 + 2], B[2 * 4 + b]);
            acc = cmac(acc, A[a * 4 + 3], B[3 * 4 + b]);
            C[a * 4 + b] = acc;
        }
    }
}

// two matvecs: w[0..3] <- M*w[0..3], w[4..7] <- M*w[4..7]
__device__ __forceinline__ void mv2(const float2* M, float2* w) {
    float2 r[8];
#pragma unroll
    for (int a = 0; a < 4; ++a) {
        float2 a0 = cmul(M[a * 4 + 0], w[0]);
        float2 a1 = cmul(M[a * 4 + 0], w[4]);
#pragma unroll
        for (int k = 1; k < 4; ++k) {
            a0 = cmac(a0, M[a * 4 + k], w[k]);
            a1 = cmac(a1, M[a * 4 + k], w[4 + k]);
        }
        r[a] = a0;
        r[4 + a] = a1;
    }
#pragma unroll
    for (int i = 0; i < 8; ++i) w[i] = r[i];
}

// ---------- vectorized 16-float2 (128B) and 8-float2 (64B) moves ----------
__device__ __forceinline__ void ld16(float2* X, const float2* p) {
    const float4* q = (const float4*)p;
#pragma unroll
    for (int i = 0; i < 8; ++i) {
        float4 t = q[i];
        X[2 * i]     = make_float2(t.x, t.y);
        X[2 * i + 1] = make_float2(t.z, t.w);
    }
}
__device__ __forceinline__ void st16(float2* p, const float2* X) {
    float4* q = (float4*)p;
#pragma unroll
    for (int i = 0; i < 8; ++i)
        q[i] = make_float4(X[2 * i].x, X[2 * i].y, X[2 * i + 1].x, X[2 * i + 1].y);
}
__device__ __forceinline__ void ld8(float2* X, const float2* p) {
    const float4* q = (const float4*)p;
#pragma unroll
    for (int i = 0; i < 4; ++i) {
        float4 t = q[i];
        X[2 * i]     = make_float2(t.x, t.y);
        X[2 * i + 1] = make_float2(t.z, t.w);
    }
}
__device__ __forceinline__ void st8(float2* p, const float2* X) {
    float4* q = (float4*)p;
#pragma unroll
    for (int i = 0; i < 4; ++i)
        q[i] = make_float4(X[2 * i].x, X[2 * i].y, X[2 * i + 1].x, X[2 * i + 1].y);
}

// ---------- U = exp(-i*dt*H) for one sample, entirely in registers ----------
__device__ __forceinline__ void expmU(float uxi, float uyi, float v1, float v2,
                                      float J, float2* X) {
    const float twopi = 6.2831855f;
    float d0 = twopi * (0.5f * (v1 + v2) + 0.25f * J);
    float d1 = twopi * (0.5f * (v1 - v2) - 0.25f * J);
    float d2 = twopi * (0.5f * (v2 - v1) - 0.25f * J);
    float d3 = twopi * (-0.5f * (v1 + v2) + 0.25f * J);
    float g  = twopi * 0.5f * J;
    float cr = 0.5f * uxi;
    float ci = -0.5f * uyi;

    // H (Hermitian):
    // [d0,  c,  c,  0 ]
    // [c*, d1,  g,  c ]
    // [c*,  g, d2,  c ]
    // [ 0, c*, c*, d3 ]
    float2 H[16];
    H[0]  = make_float2(d0, 0.f);  H[1]  = make_float2(cr, ci);
    H[2]  = make_float2(cr, ci);   H[3]  = make_float2(0.f, 0.f);
    H[4]  = make_float2(cr, -ci);  H[5]  = make_float2(d1, 0.f);
    H[6]  = make_float2(g, 0.f);   H[7]  = make_float2(cr, ci);
    H[8]  = make_float2(cr, -ci);  H[9]  = make_float2(g, 0.f);
    H[10] = make_float2(d2, 0.f);  H[11] = make_float2(cr, ci);
    H[12] = make_float2(0.f, 0.f); H[13] = make_float2(cr, -ci);
    H[14] = make_float2(cr, -ci);  H[15] = make_float2(d3, 0.f);

    // A = -i * (dt/16) * H :  (-i)*(hr + i*hi) = hi - i*hr
    const float s = DTF * (1.0f / 16.0f);
    float2 A[16];
#pragma unroll
    for (int k = 0; k < 16; ++k) A[k] = make_float2(s * H[k].y, -s * H[k].x);

    // order-6 Taylor via Horner: X = I + A/6; X = I + (A/k)*X, k=5..1
#pragma unroll
    for (int k = 0; k < 16; ++k)
        X[k] = make_float2(A[k].x * (1.f / 6.f), A[k].y * (1.f / 6.f));
    X[0].x += 1.f; X[5].x += 1.f; X[10].x += 1.f; X[15].x += 1.f;
#pragma unroll
    for (int kk = 5; kk >= 1; --kk) {
        float2 Z[16];
        mm4(A, X, Z);
        float r = 1.0f / (float)kk;
#pragma unroll
        for (int k = 0; k < 16; ++k) X[k] = make_float2(Z[k].x * r, Z[k].y * r);
        X[0].x += 1.f; X[5].x += 1.f; X[10].x += 1.f; X[15].x += 1.f;
    }
    // square 4 times (undo the /16 scaling)
#pragma unroll
    for (int q = 0; q < 4; ++q) {
        float2 Z[16];
        mm4(X, X, Z);
#pragma unroll
        for (int k = 0; k < 16; ++k) X[k] = Z[k];
    }
}

// in-LDS inclusive Hillis-Steele scan over 256 threads; X (registers) is the
// running inclusive product for this thread, S is 256*16 float2.
// combine: newer-on-the-left matrix product.
__device__ __forceinline__ void scan256(float2* X, float2* S, int t) {
    st16(S + t * 16, X);
#pragma unroll 1
    for (int off = 1; off < 256; off <<= 1) {
        __syncthreads();
        float2 Y[16];
        bool has = (t >= off);
        if (has) ld16(Y, S + (t - off) * 16);
        __syncthreads();
        if (has) {
            float2 Z[16];
            mm4(X, Y, Z);
#pragma unroll
            for (int j = 0; j < 16; ++j) X[j] = Z[j];
            st16(S + t * 16, X);
        }
    }
    __syncthreads();
}

// ---------- K1: block totals T2[g] = U_{256g+255} ... U_{256g} ----------
__global__ __launch_bounds__(256) void k_blocktot(
    const float* __restrict__ ux, const float* __restrict__ uy,
    const float* __restrict__ v1p, const float* __restrict__ v2p,
    const float* __restrict__ Jp, float2* __restrict__ T2) {
    __shared__ float2 S[256 * 16];
    int g = blockIdx.x, t = threadIdx.x;
    int n = g * 256 + t;
    float2 X[16];
    expmU(ux[n], uy[n], *v1p, *v2p, *Jp, X);
    scan256(X, S, t);
    if (t == 255) st16(T2 + (size_t)g * 16, X);
}

// ---------- K2: scan the 256 totals -> exclusive-prefix columns 0,3 ----------
__global__ __launch_bounds__(256) void k_scanT2(
    const float2* __restrict__ T2, float2* __restrict__ W2) {
    __shared__ float2 S[256 * 16];
    int t = threadIdx.x;
    float2 X[16];
    ld16(X, T2 + (size_t)t * 16);
    scan256(X, S, t);
    float2 w[8];
    if (t == 0) {
#pragma unroll
        for (int i = 0; i < 8; ++i) w[i] = make_float2(0.f, 0.f);
        w[0] = make_float2(1.f, 0.f); // col0 of I
        w[7] = make_float2(1.f, 0.f); // col3 of I
    } else {
        const float2* E = S + (t - 1) * 16; // inclusive up to t-1 = exclusive at t
#pragma unroll
        for (int a = 0; a < 4; ++a) {
            w[a]     = E[a * 4 + 0];
            w[4 + a] = E[a * 4 + 3];
        }
    }
    st8(W2 + (size_t)t * 8, w);
}

// ---------- K3: recompute U + in-block scan, apply prefix, emit Re(Mxy) ----------
__global__ __launch_bounds__(256) void k_final(
    const float* __restrict__ ux, const float* __restrict__ uy,
    const float* __restrict__ v1p, const float* __restrict__ v2p,
    const float* __restrict__ Jp, const float2* __restrict__ W2,
    float* __restrict__ out) {
    __shared__ float2 S[256 * 16];
    int g = blockIdx.x, t = threadIdx.x;
    int n = g * 256 + t;
    float2 X[16];
    expmU(ux[n], uy[n], *v1p, *v2p, *Jp, X);
    scan256(X, S, t); // X = U_n ... U_{256g}
    float2 w[8];
    ld8(w, W2 + (size_t)g * 8); // cols 0,3 of prefix before sample 256g
    mv2(X, w);                  // cols 0,3 of inclusive product P_n
    // rho_ab = w0_a conj(w0_b) - w3_a conj(w3_b)
    // m = 0.25*(rho01 + rho02 + rho13 + rho23); output = Re(m) (harness stores
    // the complex64 reference cast to float32 = real part, 65536 elements)
    float re0 = cmulc(w[0], w[1]).x + cmulc(w[0], w[2]).x +
                cmulc(w[1], w[3]).x + cmulc(w[2], w[3]).x;
    float re3 = cmulc(w[4], w[5]).x + cmulc(w[4], w[6]).x +
                cmulc(w[5], w[7]).x + cmulc(w[6], w[7]).x;
    out[n] = 0.25f * (re0 - re3);
}

extern "C" void kernel_launch(void* const* d_in, const int* in_sizes, int n_in,
                              void* d_out, int out_size, void* d_ws, size_t ws_size,
                              hipStream_t stream) {
    const float* ux = (const float*)d_in[0];
    const float* uy = (const float*)d_in[1];
    const float* v1 = (const float*)d_in[2];
    const float* v2 = (const float*)d_in[3];
    const float* J  = (const float*)d_in[4];
    float* out = (float*)d_out;

    char* ws = (char*)d_ws;
    // layout: T2 (256 * 128B = 32 KiB) | W2 (256 * 64B = 16 KiB)  -> 48 KiB total
    float2* T2 = (float2*)(ws);
    float2* W2 = (float2*)(ws + 256 * 128);

    k_blocktot<<<256, 256, 0, stream>>>(ux, uy, v1, v2, J, T2);
    k_scanT2<<<1, 256, 0, stream>>>(T2, W2);
    k_final<<<256, 256, 0, stream>>>(ux, uy, v1, v2, J, W2, out);
}

// Round 4
// 34.489 us; speedup vs baseline: 2.0623x; 2.0623x over previous
//
#include <hip/hip_runtime.h>

#define NSAMP 65536
#define DTF 1e-5f

// ---------- complex helpers (float2 = complex64) ----------
__device__ __forceinline__ float2 cmul(float2 a, float2 b) {
    return make_float2(a.x * b.x - a.y * b.y, a.x * b.y + a.y * b.x);
}
__device__ __forceinline__ float2 cmac(float2 c, float2 a, float2 b) {
    c.x += a.x * b.x - a.y * b.y;
    c.y += a.x * b.y + a.y * b.x;
    return c;
}
__device__ __forceinline__ float2 cmulc(float2 a, float2 b) { // a * conj(b)
    return make_float2(a.x * b.x + a.y * b.y, a.y * b.x - a.x * b.y);
}

// ---------- 4x4 complex matmul C = A*B (row-major, 16 float2) ----------
__device__ __forceinline__ void mm4(const float2* A, const float2* B, float2* C) {
#pragma unroll
    for (int a = 0; a < 4; ++a) {
#pragma unroll
        for (int b = 0; b < 4; ++b) {
            float2 acc = cmul(A[a * 4 + 0], B[0 * 4 + b]);
            acc = cmac(acc, A[a * 4 + 1], B[1 * 4 + b]);
            acc = cmac(acc, A[a * 4 + 2], B[2 * 4 + b]);
            acc = cmac(acc, A[a * 4 + 3], B[3 * 4 + b]);
            C[a * 4 + b] = acc;
        }
    }
}

// two matvecs: w[0..3] <- M*w[0..3], w[4..7] <- M*w[4..7]
__device__ __forceinline__ void mv2(const float2* M, float2* w) {
    float2 r[8];
#pragma unroll
    for (int a = 0; a < 4; ++a) {
        float2 a0 = cmul(M[a * 4 + 0], w[0]);
        float2 a1 = cmul(M[a * 4 + 0], w[4]);
#pragma unroll
        for (int k = 1; k < 4; ++k) {
            a0 = cmac(a0, M[a * 4 + k], w[k]);
            a1 = cmac(a1, M[a * 4 + k], w[4 + k]);
        }
        r[a] = a0;
        r[4 + a] = a1;
    }
#pragma unroll
    for (int i = 0; i < 8; ++i) w[i] = r[i];
}

// ---------- LDS/global 16-float2 (128B) and 8-float2 (64B) moves ----------
__device__ __forceinline__ void ld16(float2* X, const float2* p) {
    const float4* q = (const float4*)p;
#pragma unroll
    for (int i = 0; i < 8; ++i) {
        float4 t = q[i];
        X[2 * i]     = make_float2(t.x, t.y);
        X[2 * i + 1] = make_float2(t.z, t.w);
    }
}
__device__ __forceinline__ void st16(float2* p, const float2* X) {
    float4* q = (float4*)p;
#pragma unroll
    for (int i = 0; i < 8; ++i)
        q[i] = make_float4(X[2 * i].x, X[2 * i].y, X[2 * i + 1].x, X[2 * i + 1].y);
}
__device__ __forceinline__ void ld8(float2* X, const float2* p) {
    const float4* q = (const float4*)p;
#pragma unroll
    for (int i = 0; i < 4; ++i) {
        float4 t = q[i];
        X[2 * i]     = make_float2(t.x, t.y);
        X[2 * i + 1] = make_float2(t.z, t.w);
    }
}
__device__ __forceinline__ void st8(float2* p, const float2* X) {
    float4* q = (float4*)p;
#pragma unroll
    for (int i = 0; i < 4; ++i)
        q[i] = make_float4(X[2 * i].x, X[2 * i].y, X[2 * i + 1].x, X[2 * i + 1].y);
}

// ---------- U = exp(-i*dt*H) in registers: s=4 scaling, order-6 Taylor ----------
__device__ __forceinline__ void expmU(float uxi, float uyi, float v1, float v2,
                                      float J, float2* X) {
    const float twopi = 6.2831855f;
    float d0 = twopi * (0.5f * (v1 + v2) + 0.25f * J);
    float d1 = twopi * (0.5f * (v1 - v2) - 0.25f * J);
    float d2 = twopi * (0.5f * (v2 - v1) - 0.25f * J);
    float d3 = twopi * (-0.5f * (v1 + v2) + 0.25f * J);
    float g  = twopi * 0.5f * J;
    float cr = 0.5f * uxi;
    float ci = -0.5f * uyi;

    // H (Hermitian):
    // [d0,  c,  c,  0 ]
    // [c*, d1,  g,  c ]
    // [c*,  g, d2,  c ]
    // [ 0, c*, c*, d3 ]
    float2 H[16];
    H[0]  = make_float2(d0, 0.f);  H[1]  = make_float2(cr, ci);
    H[2]  = make_float2(cr, ci);   H[3]  = make_float2(0.f, 0.f);
    H[4]  = make_float2(cr, -ci);  H[5]  = make_float2(d1, 0.f);
    H[6]  = make_float2(g, 0.f);   H[7]  = make_float2(cr, ci);
    H[8]  = make_float2(cr, -ci);  H[9]  = make_float2(g, 0.f);
    H[10] = make_float2(d2, 0.f);  H[11] = make_float2(cr, ci);
    H[12] = make_float2(0.f, 0.f); H[13] = make_float2(cr, -ci);
    H[14] = make_float2(cr, -ci);  H[15] = make_float2(d3, 0.f);

    // A = -i * (dt/4) * H :  (-i)*(hr + i*hi) = hi - i*hr
    const float s = DTF * 0.25f;
    float2 A[16];
#pragma unroll
    for (int k = 0; k < 16; ++k) A[k] = make_float2(s * H[k].y, -s * H[k].x);

    // order-6 Taylor via Horner: X = I + A/6; X = I + (A/k)*X, k=5..1
#pragma unroll
    for (int k = 0; k < 16; ++k)
        X[k] = make_float2(A[k].x * (1.f / 6.f), A[k].y * (1.f / 6.f));
    X[0].x += 1.f; X[5].x += 1.f; X[10].x += 1.f; X[15].x += 1.f;
#pragma unroll
    for (int kk = 5; kk >= 1; --kk) {
        float2 Z[16];
        mm4(A, X, Z);
        float r = 1.0f / (float)kk;
#pragma unroll
        for (int k = 0; k < 16; ++k) X[k] = make_float2(Z[k].x * r, Z[k].y * r);
        X[0].x += 1.f; X[5].x += 1.f; X[10].x += 1.f; X[15].x += 1.f;
    }
    // square twice (undo the /4 scaling)
#pragma unroll
    for (int q = 0; q < 2; ++q) {
        float2 Z[16];
        mm4(X, X, Z);
#pragma unroll
        for (int k = 0; k < 16; ++k) X[k] = Z[k];
    }
}

// ---------- barrier-free 64-lane inclusive matrix scan via shfl_up ----------
// combine newer-on-the-left: X_l <- X_l * X_{l-off}
__device__ __forceinline__ void wave_scan(float2* X, int lane) {
#pragma unroll
    for (int off = 1; off < 64; off <<= 1) {
        float2 Y[16];
#pragma unroll
        for (int j = 0; j < 16; ++j) {
            Y[j].x = __shfl_up(X[j].x, (unsigned)off, 64);
            Y[j].y = __shfl_up(X[j].y, (unsigned)off, 64);
        }
        if (lane >= off) {
            float2 Z[16];
            mm4(X, Y, Z);
#pragma unroll
            for (int j = 0; j < 16; ++j) X[j] = Z[j];
        }
    }
}

// progressive cross-wave combine inside a 256-thread block.
// WT[w] (w=0..2) holds wave w's total. Wave w multiplies by WT[w-1..0].
__device__ __forceinline__ void block_combine(float2* X, float2 (*WT)[16],
                                              int w, int lane) {
    if (w < 3 && lane == 63) st16(&WT[w][0], X);
    __syncthreads();
    for (int k = w - 1; k >= 0; --k) {
        float2 Y[16], Z[16];
        ld16(Y, &WT[k][0]);
        mm4(X, Y, Z);
#pragma unroll
        for (int j = 0; j < 16; ++j) X[j] = Z[j];
    }
}

// ---------- K1: expm + in-block scan; store S (SoA) and block totals T ----------
__global__ __launch_bounds__(256) void k1_scan(
    const float* __restrict__ ux, const float* __restrict__ uy,
    const float* __restrict__ v1p, const float* __restrict__ v2p,
    const float* __restrict__ Jp, float2* __restrict__ S,
    float2* __restrict__ T) {
    __shared__ float2 WT[3][16];
    int bid = blockIdx.x, t = threadIdx.x;
    int lane = t & 63, w = t >> 6;
    int n = bid * 256 + t;
    float2 X[16];
    expmU(ux[n], uy[n], *v1p, *v2p, *Jp, X);
    wave_scan(X, lane);          // inclusive within wave
    block_combine(X, WT, w, lane); // inclusive within 256-sample block
#pragma unroll
    for (int j = 0; j < 16; ++j) S[(size_t)j * NSAMP + n] = X[j];
    if (t == 255) st16(T + (size_t)bid * 16, X);
}

// ---------- K2: scan 256 block totals -> exclusive-prefix cols 0,3 ----------
__global__ __launch_bounds__(256) void k2_scanT(
    const float2* __restrict__ T, float2* __restrict__ W2) {
    __shared__ float2 WT[3][16];
    __shared__ float2 SX[256][16]; // 32 KB
    int t = threadIdx.x, lane = t & 63, w = t >> 6;
    float2 X[16];
    ld16(X, T + (size_t)t * 16);
    wave_scan(X, lane);
    block_combine(X, WT, w, lane); // X = T_t * ... * T_0 (global inclusive)
    st16(&SX[t][0], X);
    __syncthreads();
    float2 wv[8];
    if (t == 0) {
#pragma unroll
        for (int i = 0; i < 8; ++i) wv[i] = make_float2(0.f, 0.f);
        wv[0] = make_float2(1.f, 0.f); // col0 of I
        wv[7] = make_float2(1.f, 0.f); // col3 of I
    } else {
        const float2* E = &SX[t - 1][0]; // exclusive at t
#pragma unroll
        for (int a = 0; a < 4; ++a) {
            wv[a]     = E[a * 4 + 0];
            wv[4 + a] = E[a * 4 + 3];
        }
    }
    st8(W2 + (size_t)t * 8, wv);
}

// ---------- K3: apply prefix to stored scan matrices, emit Re(Mxy) ----------
__global__ __launch_bounds__(256) void k3_apply(
    const float2* __restrict__ S, const float2* __restrict__ W2,
    float* __restrict__ out) {
    int n = blockIdx.x * 256 + threadIdx.x;
    int g = n >> 8;
    float2 M[16];
#pragma unroll
    for (int j = 0; j < 16; ++j) M[j] = S[(size_t)j * NSAMP + n];
    float2 wv[8];
    ld8(wv, W2 + (size_t)g * 8); // cols 0,3 of global prefix before block g
    mv2(M, wv);                  // cols 0,3 of inclusive product P_n
    // rho_ab = w0_a conj(w0_b) - w3_a conj(w3_b)
    // out = Re(0.25*(rho01 + rho02 + rho13 + rho23))
    float re0 = cmulc(wv[0], wv[1]).x + cmulc(wv[0], wv[2]).x +
                cmulc(wv[1], wv[3]).x + cmulc(wv[2], wv[3]).x;
    float re3 = cmulc(wv[4], wv[5]).x + cmulc(wv[4], wv[6]).x +
                cmulc(wv[5], wv[7]).x + cmulc(wv[6], wv[7]).x;
    out[n] = 0.25f * (re0 - re3);
}

extern "C" void kernel_launch(void* const* d_in, const int* in_sizes, int n_in,
                              void* d_out, int out_size, void* d_ws, size_t ws_size,
                              hipStream_t stream) {
    const float* ux = (const float*)d_in[0];
    const float* uy = (const float*)d_in[1];
    const float* v1 = (const float*)d_in[2];
    const float* v2 = (const float*)d_in[3];
    const float* J  = (const float*)d_in[4];
    float* out = (float*)d_out;

    char* ws = (char*)d_ws;
    // layout: S (16 planes * 65536 float2 = 8 MiB) | T (32 KiB) | W2 (16 KiB)
    float2* S  = (float2*)(ws);
    float2* T  = (float2*)(ws + (size_t)16 * NSAMP * 8);
    float2* W2 = (float2*)(ws + (size_t)16 * NSAMP * 8 + 256 * 128);

    k1_scan<<<NSAMP / 256, 256, 0, stream>>>(ux, uy, v1, v2, J, S, T);
    k2_scanT<<<1, 256, 0, stream>>>(T, W2);
    k3_apply<<<NSAMP / 256, 256, 0, stream>>>(S, W2, out);
}